// Round 1
// baseline (80598.059 us; speedup 1.0000x reference)
//
#include <hip/hip_runtime.h>
#include <hip/hip_bf16.h>

#define BB 256
#define TT 2000
#define FF 42
#define NTHREADS 640

__device__ __forceinline__ float bf2f(__hip_bfloat16 v) { return __bfloat162float(v); }
__device__ __forceinline__ float sig(float x) { return 1.0f / (1.0f + __expf(-x)); }
__device__ __forceinline__ float tanh_fast(float x) {
    float e = __expf(2.0f * x);
    return 1.0f - 2.0f / (e + 1.0f);
}
__device__ __forceinline__ float unpk_lo(unsigned u) {
    union { unsigned u; float f; } c; c.u = u << 16; return c.f;
}
__device__ __forceinline__ float unpk_hi(unsigned u) {
    union { unsigned u; float f; } c; c.u = u & 0xffff0000u; return c.f;
}
// fp32 -> bf16 bits, round-to-nearest-even
__device__ __forceinline__ unsigned f2bfbits(float f) {
    union { float f; unsigned u; } c; c.f = f;
    unsigned r = c.u + 0x7FFFu + ((c.u >> 16) & 1u);
    return r >> 16;
}
__device__ __forceinline__ unsigned pack2(float a, float b) {
    return f2bfbits(a) | (f2bfbits(b) << 16);
}
__device__ __forceinline__ float gld(const void* p, int i, bool f32) {
    return f32 ? ((const float*)p)[i] : bf2f(((const __hip_bfloat16*)p)[i]);
}

// packed bf16 weight (registers) · fp32 input (LDS float4 broadcast), 4 acc chains
template<int NF4>
__device__ __forceinline__ float dot4(const unsigned* w, const float4* in, float acc) {
    float a0 = acc, a1 = 0.f, a2 = 0.f, a3 = 0.f;
    #pragma unroll
    for (int i = 0; i < NF4; ++i) {
        float4 d = in[i];
        unsigned u0 = w[2 * i], u1 = w[2 * i + 1];
        a0 = fmaf(unpk_lo(u0), d.x, a0);
        a1 = fmaf(unpk_hi(u0), d.y, a1);
        a2 = fmaf(unpk_lo(u1), d.z, a2);
        a3 = fmaf(unpk_hi(u1), d.w, a3);
    }
    return (a0 + a1) + (a2 + a3);
}

__global__ __launch_bounds__(NTHREADS, 3)
void rnn_fused(const void* __restrict__ x,
               const void* __restrict__ dense_w, const void* __restrict__ dense_b,
               const void* __restrict__ vad_w_ih, const void* __restrict__ vad_w_hh,
               const void* __restrict__ vad_b_ih, const void* __restrict__ vad_b_hh,
               const void* __restrict__ vad_out_w, const void* __restrict__ vad_out_b,
               const void* __restrict__ noise_w_ih, const void* __restrict__ noise_w_hh,
               const void* __restrict__ noise_b_ih, const void* __restrict__ noise_b_hh,
               const void* __restrict__ den_w_ih, const void* __restrict__ den_w_hh,
               const void* __restrict__ den_b_ih, const void* __restrict__ den_b_hh,
               const void* __restrict__ out_w, const void* __restrict__ out_b,
               void* __restrict__ d_out) {
    // ---- LDS (~6 KiB): only activations/state/partials; weights live in VGPRs ----
    __shared__ __align__(16) float sXT[44];    // x(t) fp32 (+pad zeros)
    __shared__ __align__(16) float sTMP[24];   // dense out
    __shared__ __align__(16) float sHV[24];    // h_vad
    __shared__ __align__(16) float sHN[48];    // h_noise
    __shared__ __align__(16) float sHD[96];    // h_den
    __shared__ __align__(16) float sHR[96];    // relu(h_den)
    __shared__ __align__(16) float sNIN[92];   // [tmp | vad | x] (+pad)
    __shared__ __align__(16) float sDIN[116];  // [vad | relu(noise) | x] (+pad)
    __shared__ float sNPI[144], sNPH[144];     // noise partials
    __shared__ float sGI[288], sGH[288];       // den partials
    __shared__ int sBad;

    const int tid = threadIdx.x;
    const int b = blockIdx.x;
    const int nt = NTHREADS;

    // ---- dtype detection (validated in earlier rounds) ----
    if (tid == 0) sBad = 0;
    __syncthreads();
    {
        const unsigned* w = (const unsigned*)dense_w;
        for (int i = tid; i < 500; i += nt) {
            float av = fabsf(unpk_lo(w[i]));
            if (!(av <= 1e3f)) { atomicAdd(&sBad, 1); break; }
        }
    }
    __syncthreads();
    const bool F32 = (sBad > 0);

    const float* xbf = (const float*)x + (size_t)b * TT * FF;
    const __hip_bfloat16* xbh = (const __hip_bfloat16*)x + (size_t)b * TT * FF;
    float* odf = (float*)d_out;
    __hip_bfloat16* odh = (__hip_bfloat16*)d_out;
    float* ovf = odf + (size_t)BB * TT * 22;
    __hip_bfloat16* ovh = odh + (size_t)BB * TT * 22;

    // ---- role-partitioned weight registers ----
    // tid   0-287: wreg[0..57]  = den_w_ih row tid (57w + zero pad)
    // tid  96-119:   + wreg[58..79] = dense row (tid-96) (21w + pad)
    // tid 288-311: wreg[0..71]  = vad fused: 3 ih rows, 3 hh rows (12w each)
    // tid     312: wreg[0..11]  = vad_out row
    // tid 320-607: wreg[0..47]  = den_w_hh row (tid-320)
    // tid 320-463:   + wreg[48..93] = noise_w_ih row (tid-320) (45w + pad)
    // tid 464-607:   + wreg[48..71] = noise_w_hh row (tid-464)
    // tid 608-629: wreg[0..47]  = out_w row (tid-608)
    unsigned wreg[94];
    #pragma unroll
    for (int i = 0; i < 94; ++i) wreg[i] = 0u;
    float b_main = 0.f, b_aux = 0.f;
    float bv0 = 0.f, bv1 = 0.f, bv2 = 0.f, bv3 = 0.f, bv4 = 0.f, bv5 = 0.f;
    float hvreg = 0.f;

    if (tid < 288) {
        #pragma unroll
        for (int i = 0; i < 57; ++i)
            wreg[i] = pack2(gld(den_w_ih, tid * 114 + 2 * i, F32),
                            gld(den_w_ih, tid * 114 + 2 * i + 1, F32));
        b_main = gld(den_b_ih, tid, F32);
        if (tid >= 96 && tid < 120) {
            int o = tid - 96;
            #pragma unroll
            for (int i = 0; i < 21; ++i)
                wreg[58 + i] = pack2(gld(dense_w, o * 42 + 2 * i, F32),
                                     gld(dense_w, o * 42 + 2 * i + 1, F32));
            b_aux = gld(dense_b, o, F32);
        }
    } else if (tid < 312) {
        int o = tid - 288;
        #pragma unroll
        for (int g = 0; g < 3; ++g) {
            #pragma unroll
            for (int i = 0; i < 12; ++i) {
                wreg[g * 12 + i]      = pack2(gld(vad_w_ih, (g * 24 + o) * 24 + 2 * i, F32),
                                              gld(vad_w_ih, (g * 24 + o) * 24 + 2 * i + 1, F32));
                wreg[36 + g * 12 + i] = pack2(gld(vad_w_hh, (g * 24 + o) * 24 + 2 * i, F32),
                                              gld(vad_w_hh, (g * 24 + o) * 24 + 2 * i + 1, F32));
            }
        }
        bv0 = gld(vad_b_ih, o, F32);      bv1 = gld(vad_b_ih, 24 + o, F32);
        bv2 = gld(vad_b_ih, 48 + o, F32); bv3 = gld(vad_b_hh, o, F32);
        bv4 = gld(vad_b_hh, 24 + o, F32); bv5 = gld(vad_b_hh, 48 + o, F32);
    } else if (tid == 312) {
        #pragma unroll
        for (int i = 0; i < 12; ++i)
            wreg[i] = pack2(gld(vad_out_w, 2 * i, F32), gld(vad_out_w, 2 * i + 1, F32));
        b_main = gld(vad_out_b, 0, F32);
    } else if (tid >= 320 && tid < 608) {
        int o = tid - 320;
        #pragma unroll
        for (int i = 0; i < 48; ++i)
            wreg[i] = pack2(gld(den_w_hh, o * 96 + 2 * i, F32),
                            gld(den_w_hh, o * 96 + 2 * i + 1, F32));
        b_main = gld(den_b_hh, o, F32);
        if (o < 144) {
            #pragma unroll
            for (int i = 0; i < 45; ++i)
                wreg[48 + i] = pack2(gld(noise_w_ih, o * 90 + 2 * i, F32),
                                     gld(noise_w_ih, o * 90 + 2 * i + 1, F32));
            b_aux = gld(noise_b_ih, o, F32);
        } else {
            int o2 = o - 144;
            #pragma unroll
            for (int i = 0; i < 24; ++i)
                wreg[48 + i] = pack2(gld(noise_w_hh, o2 * 48 + 2 * i, F32),
                                     gld(noise_w_hh, o2 * 48 + 2 * i + 1, F32));
            b_aux = gld(noise_b_hh, o2, F32);
        }
    } else if (tid >= 608 && tid < 630) {
        int o = tid - 608;
        #pragma unroll
        for (int i = 0; i < 48; ++i)
            wreg[i] = pack2(gld(out_w, o * 96 + 2 * i, F32),
                            gld(out_w, o * 96 + 2 * i + 1, F32));
        b_main = gld(out_b, o, F32);
    }

    // ---- prologue: zero state, stage x(0), prefetch x(1) ----
    for (int i = tid; i < 24; i += nt) { sHV[i] = 0.f; sTMP[i] = 0.f; }
    for (int i = tid; i < 48; i += nt) sHN[i] = 0.f;
    for (int i = tid; i < 96; i += nt) { sHD[i] = 0.f; sHR[i] = 0.f; }
    if (tid < 2) { sXT[42 + tid] = 0.f; sNIN[90 + tid] = 0.f; sDIN[114 + tid] = 0.f; }
    if (tid < FF) {
        float v = F32 ? xbf[tid] : bf2f(xbh[tid]);
        sXT[tid] = v; sNIN[48 + tid] = v; sDIN[72 + tid] = v;
    }
    float xreg = 0.f;
    if (tid >= 464 && tid < 464 + FF) {
        int j = tid - 464;
        xreg = F32 ? xbf[FF + j] : bf2f(xbh[FF + j]);
    }
    __syncthreads();
    // dense(0)
    if (tid >= 96 && tid < 120) {
        int o = tid - 96;
        float v = tanh_fast(dot4<11>(wreg + 58, (const float4*)sXT, b_aux));
        sTMP[o] = v; sNIN[o] = v;
    }
    __syncthreads();

    for (int t = 0; t < TT; ++t) {
        // ---- S2: den hh [waves 5-9] || vad fused GRU [wave 4] || out head(t-1) [wave 9 hi] ----
        if (tid >= 320 && tid < 608) {
            sGH[tid - 320] = dot4<24>(wreg, (const float4*)sHD, b_main);
        } else if (tid >= 288 && tid < 312) {
            // all 24 vad threads are in wave 4: lockstep read-then-write of sHV is safe
            int o = tid - 288;
            const float4* tmp4 = (const float4*)sTMP;
            const float4* hv4 = (const float4*)sHV;
            float xr = dot4<6>(wreg + 0,  tmp4, bv0);
            float xz = dot4<6>(wreg + 12, tmp4, bv1);
            float xn = dot4<6>(wreg + 24, tmp4, bv2);
            float hr = dot4<6>(wreg + 36, hv4, bv3);
            float hz = dot4<6>(wreg + 48, hv4, bv4);
            float hn = dot4<6>(wreg + 60, hv4, bv5);
            float r = sig(xr + hr);
            float z = sig(xz + hz);
            float n = tanh_fast(xn + r * hn);
            float h = (1.f - z) * n + z * hvreg;
            hvreg = h;
            sHV[o] = h; sNIN[24 + o] = h; sDIN[o] = h;
        } else if (tid >= 608 && tid < 630) {
            if (t > 0) {
                int o = tid - 608;
                float v = sig(dot4<24>(wreg, (const float4*)sHR, b_main));
                size_t oi = ((size_t)b * TT + (t - 1)) * 22 + o;
                if (F32) odf[oi] = v; else odh[oi] = __float2bfloat16(v);
            }
        }
        __syncthreads();

        // ---- S3: noise ih [waves 5-7] || noise hh [waves 7-9] || vad_out(t) ----
        if (tid >= 320 && tid < 464) {
            sNPI[tid - 320] = dot4<23>(wreg + 48, (const float4*)sNIN, b_aux);
        } else if (tid >= 464 && tid < 608) {
            sNPH[tid - 464] = dot4<12>(wreg + 48, (const float4*)sHN, b_aux);
        } else if (tid == 312) {
            float v = sig(dot4<6>(wreg, (const float4*)sHV, b_main));
            size_t oi = (size_t)b * TT + t;
            if (F32) ovf[oi] = v; else ovh[oi] = __float2bfloat16(v);
        }
        __syncthreads();

        // ---- S4: noise update [wave 0] ----
        if (tid < 48) {
            float r = sig(sNPI[tid] + sNPH[tid]);
            float z = sig(sNPI[48 + tid] + sNPH[48 + tid]);
            float n = tanh_fast(sNPI[96 + tid] + r * sNPH[96 + tid]);
            float h = (1.f - z) * n + z * sHN[tid];
            sHN[tid] = h;
            sDIN[24 + tid] = fmaxf(h, 0.f);
        }
        __syncthreads();

        // ---- S5: den ih [waves 0-4] || x(t+1) -> sXT,sNIN [wave 7] ----
        if (tid < 288) {
            sGI[tid] = dot4<29>(wreg, (const float4*)sDIN, b_main);
        } else if (tid >= 464 && tid < 464 + FF) {
            int j = tid - 464;
            sXT[j] = xreg; sNIN[48 + j] = xreg;
            int t2 = (t + 2 < TT) ? (t + 2) : (TT - 1);
            xreg = F32 ? xbf[t2 * FF + j] : bf2f(xbh[t2 * FF + j]);
        }
        __syncthreads();

        // ---- S6: den update [waves 0-1] || dense(t+1) [w1/w2] || x->sDIN [wave 2] ----
        if (tid < 96) {
            float r = sig(sGI[tid] + sGH[tid]);
            float z = sig(sGI[96 + tid] + sGH[96 + tid]);
            float n = tanh_fast(sGI[192 + tid] + r * sGH[192 + tid]);
            float h = (1.f - z) * n + z * sHD[tid];
            sHD[tid] = h;
            sHR[tid] = fmaxf(h, 0.f);
        } else if (tid < 120) {
            int o = tid - 96;
            float v = tanh_fast(dot4<11>(wreg + 58, (const float4*)sXT, b_aux));
            sTMP[o] = v; sNIN[o] = v;
        } else if (tid >= 128 && tid < 128 + FF) {
            int j = tid - 128;
            sDIN[72 + j] = sXT[j];
        }
        __syncthreads();
    }

    // ---- epilogue: out head for t = TT-1 ----
    if (tid >= 608 && tid < 630) {
        int o = tid - 608;
        float v = sig(dot4<24>(wreg, (const float4*)sHR, b_main));
        size_t oi = ((size_t)b * TT + (TT - 1)) * 22 + o;
        if (F32) odf[oi] = v; else odh[oi] = __float2bfloat16(v);
    }
}

extern "C" void kernel_launch(void* const* d_in, const int* in_sizes, int n_in,
                              void* d_out, int out_size, void* d_ws, size_t ws_size,
                              hipStream_t stream) {
    hipLaunchKernelGGL(rnn_fused, dim3(BB), dim3(NTHREADS), 0, stream,
                       d_in[0], d_in[1], d_in[2],
                       d_in[3], d_in[4], d_in[5], d_in[6],
                       d_in[7], d_in[8],
                       d_in[9], d_in[10], d_in[11], d_in[12],
                       d_in[13], d_in[14], d_in[15], d_in[16],
                       d_in[17], d_in[18], d_out);
}

// Round 2
// 79384.003 us; speedup vs baseline: 1.0153x; 1.0153x over previous
//
#include <hip/hip_runtime.h>
#include <hip/hip_bf16.h>

#define BB 256
#define TT 2000
#define FF 42
#define NTHREADS 640

__device__ __forceinline__ float bf2f(__hip_bfloat16 v) { return __bfloat162float(v); }
__device__ __forceinline__ float sig(float x) { return 1.0f / (1.0f + __expf(-x)); }
__device__ __forceinline__ float tanh_fast(float x) {
    float e = __expf(2.0f * x);
    return 1.0f - 2.0f / (e + 1.0f);
}
__device__ __forceinline__ float unpk_lo(unsigned u) {
    union { unsigned u; float f; } c; c.u = u << 16; return c.f;
}
__device__ __forceinline__ float unpk_hi(unsigned u) {
    union { unsigned u; float f; } c; c.u = u & 0xffff0000u; return c.f;
}
// fp32 -> bf16 bits, round-to-nearest-even
__device__ __forceinline__ unsigned f2bfbits(float f) {
    union { float f; unsigned u; } c; c.f = f;
    unsigned r = c.u + 0x7FFFu + ((c.u >> 16) & 1u);
    return r >> 16;
}
__device__ __forceinline__ unsigned pack2(float a, float b) {
    return f2bfbits(a) | (f2bfbits(b) << 16);
}
__device__ __forceinline__ float gld(const void* p, int i, bool f32) {
    return f32 ? ((const float*)p)[i] : bf2f(((const __hip_bfloat16*)p)[i]);
}

#define NWREG 94

// packed bf16 weights (register array, compile-time offset OFF) · fp32 input
// (LDS float4 broadcast), 4 acc chains. Array-reference + constant indices so
// SROA keeps the array in VGPRs (round-1 lesson: pointer form -> scratch).
template<int OFF, int NF4>
__device__ __forceinline__ float dot4(const unsigned (&w)[NWREG], const float4* in, float acc) {
    float a0 = acc, a1 = 0.f, a2 = 0.f, a3 = 0.f;
    #pragma unroll
    for (int i = 0; i < NF4; ++i) {
        float4 d = in[i];
        unsigned u0 = w[OFF + 2 * i], u1 = w[OFF + 2 * i + 1];
        a0 = fmaf(unpk_lo(u0), d.x, a0);
        a1 = fmaf(unpk_hi(u0), d.y, a1);
        a2 = fmaf(unpk_lo(u1), d.z, a2);
        a3 = fmaf(unpk_hi(u1), d.w, a3);
    }
    return (a0 + a1) + (a2 + a3);
}

__global__ __launch_bounds__(NTHREADS, 3)
void rnn_fused(const void* __restrict__ x,
               const void* __restrict__ dense_w, const void* __restrict__ dense_b,
               const void* __restrict__ vad_w_ih, const void* __restrict__ vad_w_hh,
               const void* __restrict__ vad_b_ih, const void* __restrict__ vad_b_hh,
               const void* __restrict__ vad_out_w, const void* __restrict__ vad_out_b,
               const void* __restrict__ noise_w_ih, const void* __restrict__ noise_w_hh,
               const void* __restrict__ noise_b_ih, const void* __restrict__ noise_b_hh,
               const void* __restrict__ den_w_ih, const void* __restrict__ den_w_hh,
               const void* __restrict__ den_b_ih, const void* __restrict__ den_b_hh,
               const void* __restrict__ out_w, const void* __restrict__ out_b,
               void* __restrict__ d_out) {
    // ---- LDS (~6 KiB): only activations/state/partials; weights live in VGPRs ----
    __shared__ __align__(16) float sXT[44];    // x(t) fp32 (+pad zeros)
    __shared__ __align__(16) float sTMP[24];   // dense out
    __shared__ __align__(16) float sHV[24];    // h_vad
    __shared__ __align__(16) float sHN[48];    // h_noise
    __shared__ __align__(16) float sHD[96];    // h_den
    __shared__ __align__(16) float sHR[96];    // relu(h_den)
    __shared__ __align__(16) float sNIN[92];   // [tmp | vad | x] (+pad)
    __shared__ __align__(16) float sDIN[116];  // [vad | relu(noise) | x] (+pad)
    __shared__ float sNPI[144], sNPH[144];     // noise partials
    __shared__ float sGI[288], sGH[288];       // den partials
    __shared__ int sBad;

    const int tid = threadIdx.x;
    const int b = blockIdx.x;
    const int nt = NTHREADS;

    // ---- dtype detection (validated in earlier rounds) ----
    if (tid == 0) sBad = 0;
    __syncthreads();
    {
        const unsigned* w = (const unsigned*)dense_w;
        for (int i = tid; i < 500; i += nt) {
            float av = fabsf(unpk_lo(w[i]));
            if (!(av <= 1e3f)) { atomicAdd(&sBad, 1); break; }
        }
    }
    __syncthreads();
    const bool F32 = (sBad > 0);

    const float* xbf = (const float*)x + (size_t)b * TT * FF;
    const __hip_bfloat16* xbh = (const __hip_bfloat16*)x + (size_t)b * TT * FF;
    float* odf = (float*)d_out;
    __hip_bfloat16* odh = (__hip_bfloat16*)d_out;
    float* ovf = odf + (size_t)BB * TT * 22;
    __hip_bfloat16* ovh = odh + (size_t)BB * TT * 22;

    // ---- role-partitioned weight registers ----
    // tid   0-287: wreg[0..57]  = den_w_ih row tid (57w + zero pad)
    // tid  96-119:   + wreg[58..79] = dense row (tid-96) (21w + pad)
    // tid 288-311: wreg[0..71]  = vad fused: 3 ih rows, 3 hh rows (12w each)
    // tid     312: wreg[0..11]  = vad_out row
    // tid 320-607: wreg[0..47]  = den_w_hh row (tid-320)
    // tid 320-463:   + wreg[48..93] = noise_w_ih row (tid-320) (45w + pad)
    // tid 464-607:   + wreg[48..71] = noise_w_hh row (tid-464)
    // tid 608-629: wreg[0..47]  = out_w row (tid-608)
    unsigned wreg[NWREG];
    #pragma unroll
    for (int i = 0; i < NWREG; ++i) wreg[i] = 0u;
    float b_main = 0.f, b_aux = 0.f;
    float bv0 = 0.f, bv1 = 0.f, bv2 = 0.f, bv3 = 0.f, bv4 = 0.f, bv5 = 0.f;
    float hvreg = 0.f;

    if (tid < 288) {
        #pragma unroll
        for (int i = 0; i < 57; ++i)
            wreg[i] = pack2(gld(den_w_ih, tid * 114 + 2 * i, F32),
                            gld(den_w_ih, tid * 114 + 2 * i + 1, F32));
        b_main = gld(den_b_ih, tid, F32);
        if (tid >= 96 && tid < 120) {
            int o = tid - 96;
            #pragma unroll
            for (int i = 0; i < 21; ++i)
                wreg[58 + i] = pack2(gld(dense_w, o * 42 + 2 * i, F32),
                                     gld(dense_w, o * 42 + 2 * i + 1, F32));
            b_aux = gld(dense_b, o, F32);
        }
    } else if (tid < 312) {
        int o = tid - 288;
        #pragma unroll
        for (int g = 0; g < 3; ++g) {
            #pragma unroll
            for (int i = 0; i < 12; ++i) {
                wreg[g * 12 + i]      = pack2(gld(vad_w_ih, (g * 24 + o) * 24 + 2 * i, F32),
                                              gld(vad_w_ih, (g * 24 + o) * 24 + 2 * i + 1, F32));
                wreg[36 + g * 12 + i] = pack2(gld(vad_w_hh, (g * 24 + o) * 24 + 2 * i, F32),
                                              gld(vad_w_hh, (g * 24 + o) * 24 + 2 * i + 1, F32));
            }
        }
        bv0 = gld(vad_b_ih, o, F32);      bv1 = gld(vad_b_ih, 24 + o, F32);
        bv2 = gld(vad_b_ih, 48 + o, F32); bv3 = gld(vad_b_hh, o, F32);
        bv4 = gld(vad_b_hh, 24 + o, F32); bv5 = gld(vad_b_hh, 48 + o, F32);
    } else if (tid == 312) {
        #pragma unroll
        for (int i = 0; i < 12; ++i)
            wreg[i] = pack2(gld(vad_out_w, 2 * i, F32), gld(vad_out_w, 2 * i + 1, F32));
        b_main = gld(vad_out_b, 0, F32);
    } else if (tid >= 320 && tid < 608) {
        int o = tid - 320;
        #pragma unroll
        for (int i = 0; i < 48; ++i)
            wreg[i] = pack2(gld(den_w_hh, o * 96 + 2 * i, F32),
                            gld(den_w_hh, o * 96 + 2 * i + 1, F32));
        b_main = gld(den_b_hh, o, F32);
        if (o < 144) {
            #pragma unroll
            for (int i = 0; i < 45; ++i)
                wreg[48 + i] = pack2(gld(noise_w_ih, o * 90 + 2 * i, F32),
                                     gld(noise_w_ih, o * 90 + 2 * i + 1, F32));
            b_aux = gld(noise_b_ih, o, F32);
        } else {
            int o2 = o - 144;
            #pragma unroll
            for (int i = 0; i < 24; ++i)
                wreg[48 + i] = pack2(gld(noise_w_hh, o2 * 48 + 2 * i, F32),
                                     gld(noise_w_hh, o2 * 48 + 2 * i + 1, F32));
            b_aux = gld(noise_b_hh, o2, F32);
        }
    } else if (tid >= 608 && tid < 630) {
        int o = tid - 608;
        #pragma unroll
        for (int i = 0; i < 48; ++i)
            wreg[i] = pack2(gld(out_w, o * 96 + 2 * i, F32),
                            gld(out_w, o * 96 + 2 * i + 1, F32));
        b_main = gld(out_b, o, F32);
    }

    // ---- prologue: zero state, stage x(0), prefetch x(1) ----
    for (int i = tid; i < 24; i += nt) { sHV[i] = 0.f; sTMP[i] = 0.f; }
    for (int i = tid; i < 48; i += nt) sHN[i] = 0.f;
    for (int i = tid; i < 96; i += nt) { sHD[i] = 0.f; sHR[i] = 0.f; }
    if (tid < 2) { sXT[42 + tid] = 0.f; sNIN[90 + tid] = 0.f; sDIN[114 + tid] = 0.f; }
    if (tid < FF) {
        float v = F32 ? xbf[tid] : bf2f(xbh[tid]);
        sXT[tid] = v; sNIN[48 + tid] = v; sDIN[72 + tid] = v;
    }
    float xreg = 0.f;
    if (tid >= 464 && tid < 464 + FF) {
        int j = tid - 464;
        xreg = F32 ? xbf[FF + j] : bf2f(xbh[FF + j]);
    }
    __syncthreads();
    // dense(0)
    if (tid >= 96 && tid < 120) {
        int o = tid - 96;
        float v = tanh_fast(dot4<58, 11>(wreg, (const float4*)sXT, b_aux));
        sTMP[o] = v; sNIN[o] = v;
    }
    __syncthreads();

    for (int t = 0; t < TT; ++t) {
        // ---- S2: den hh [waves 5-9] || vad fused GRU [wave 4] || out head(t-1) [wave 9 hi] ----
        if (tid >= 320 && tid < 608) {
            sGH[tid - 320] = dot4<0, 24>(wreg, (const float4*)sHD, b_main);
        } else if (tid >= 288 && tid < 312) {
            // all 24 vad threads are in wave 4: lockstep read-then-write of sHV is safe
            int o = tid - 288;
            const float4* tmp4 = (const float4*)sTMP;
            const float4* hv4 = (const float4*)sHV;
            float xr = dot4<0,  6>(wreg, tmp4, bv0);
            float xz = dot4<12, 6>(wreg, tmp4, bv1);
            float xn = dot4<24, 6>(wreg, tmp4, bv2);
            float hr = dot4<36, 6>(wreg, hv4, bv3);
            float hz = dot4<48, 6>(wreg, hv4, bv4);
            float hn = dot4<60, 6>(wreg, hv4, bv5);
            float r = sig(xr + hr);
            float z = sig(xz + hz);
            float n = tanh_fast(xn + r * hn);
            float h = (1.f - z) * n + z * hvreg;
            hvreg = h;
            sHV[o] = h; sNIN[24 + o] = h; sDIN[o] = h;
        } else if (tid >= 608 && tid < 630) {
            if (t > 0) {
                int o = tid - 608;
                float v = sig(dot4<0, 24>(wreg, (const float4*)sHR, b_main));
                size_t oi = ((size_t)b * TT + (t - 1)) * 22 + o;
                if (F32) odf[oi] = v; else odh[oi] = __float2bfloat16(v);
            }
        }
        __syncthreads();

        // ---- S3: noise ih [waves 5-7] || noise hh [waves 7-9] || vad_out(t) ----
        if (tid >= 320 && tid < 464) {
            sNPI[tid - 320] = dot4<48, 23>(wreg, (const float4*)sNIN, b_aux);
        } else if (tid >= 464 && tid < 608) {
            sNPH[tid - 464] = dot4<48, 12>(wreg, (const float4*)sHN, b_aux);
        } else if (tid == 312) {
            float v = sig(dot4<0, 6>(wreg, (const float4*)sHV, b_main));
            size_t oi = (size_t)b * TT + t;
            if (F32) ovf[oi] = v; else ovh[oi] = __float2bfloat16(v);
        }
        __syncthreads();

        // ---- S4: noise update [wave 0] ----
        if (tid < 48) {
            float r = sig(sNPI[tid] + sNPH[tid]);
            float z = sig(sNPI[48 + tid] + sNPH[48 + tid]);
            float n = tanh_fast(sNPI[96 + tid] + r * sNPH[96 + tid]);
            float h = (1.f - z) * n + z * sHN[tid];
            sHN[tid] = h;
            sDIN[24 + tid] = fmaxf(h, 0.f);
        }
        __syncthreads();

        // ---- S5: den ih [waves 0-4] || x(t+1) -> sXT,sNIN [wave 7] ----
        if (tid < 288) {
            sGI[tid] = dot4<0, 29>(wreg, (const float4*)sDIN, b_main);
        } else if (tid >= 464 && tid < 464 + FF) {
            int j = tid - 464;
            sXT[j] = xreg; sNIN[48 + j] = xreg;
            int t2 = (t + 2 < TT) ? (t + 2) : (TT - 1);
            xreg = F32 ? xbf[t2 * FF + j] : bf2f(xbh[t2 * FF + j]);
        }
        __syncthreads();

        // ---- S6: den update [waves 0-1] || dense(t+1) [w1/w2] || x->sDIN [wave 2] ----
        if (tid < 96) {
            float r = sig(sGI[tid] + sGH[tid]);
            float z = sig(sGI[96 + tid] + sGH[96 + tid]);
            float n = tanh_fast(sGI[192 + tid] + r * sGH[192 + tid]);
            float h = (1.f - z) * n + z * sHD[tid];
            sHD[tid] = h;
            sHR[tid] = fmaxf(h, 0.f);
        } else if (tid < 120) {
            int o = tid - 96;
            float v = tanh_fast(dot4<58, 11>(wreg, (const float4*)sXT, b_aux));
            sTMP[o] = v; sNIN[o] = v;
        } else if (tid >= 128 && tid < 128 + FF) {
            int j = tid - 128;
            sDIN[72 + j] = sXT[j];
        }
        __syncthreads();
    }

    // ---- epilogue: out head for t = TT-1 ----
    if (tid >= 608 && tid < 630) {
        int o = tid - 608;
        float v = sig(dot4<0, 24>(wreg, (const float4*)sHR, b_main));
        size_t oi = ((size_t)b * TT + (TT - 1)) * 22 + o;
        if (F32) odf[oi] = v; else odh[oi] = __float2bfloat16(v);
    }
}

extern "C" void kernel_launch(void* const* d_in, const int* in_sizes, int n_in,
                              void* d_out, int out_size, void* d_ws, size_t ws_size,
                              hipStream_t stream) {
    hipLaunchKernelGGL(rnn_fused, dim3(BB), dim3(NTHREADS), 0, stream,
                       d_in[0], d_in[1], d_in[2],
                       d_in[3], d_in[4], d_in[5], d_in[6],
                       d_in[7], d_in[8],
                       d_in[9], d_in[10], d_in[11], d_in[12],
                       d_in[13], d_in[14], d_in[15], d_in[16],
                       d_in[17], d_in[18], d_out);
}

// Round 3
// 78523.328 us; speedup vs baseline: 1.0264x; 1.0110x over previous
//
#include <hip/hip_runtime.h>
#include <hip/hip_bf16.h>

#define BB 256
#define TT 2000
#define FF 42
#define NTHREADS 640

__device__ __forceinline__ float bf2f(__hip_bfloat16 v) { return __bfloat162float(v); }
__device__ __forceinline__ float sig(float x) { return 1.0f / (1.0f + __expf(-x)); }
__device__ __forceinline__ float tanh_fast(float x) {
    float e = __expf(2.0f * x);
    return 1.0f - 2.0f / (e + 1.0f);
}
__device__ __forceinline__ float unpk_lo(unsigned u) {
    union { unsigned u; float f; } c; c.u = u << 16; return c.f;
}
__device__ __forceinline__ float unpk_hi(unsigned u) {
    union { unsigned u; float f; } c; c.u = u & 0xffff0000u; return c.f;
}
// fp32 -> bf16 bits, round-to-nearest-even
__device__ __forceinline__ unsigned f2bfbits(float f) {
    union { float f; unsigned u; } c; c.f = f;
    unsigned r = c.u + 0x7FFFu + ((c.u >> 16) & 1u);
    return r >> 16;
}
__device__ __forceinline__ unsigned pack2(float a, float b) {
    return f2bfbits(a) | (f2bfbits(b) << 16);
}
__device__ __forceinline__ float gld(const void* p, int i, bool f32) {
    return f32 ? ((const float*)p)[i] : bf2f(((const __hip_bfloat16*)p)[i]);
}

#define NWREG 94

// packed bf16 weights (register array, compile-time offset OFF) · fp32 input
// (LDS float4 broadcast), 4 acc chains. Array-reference + constant indices so
// SROA keeps the array in VGPRs. NOTE: requires __launch_bounds__(.,1) —
// round-1/2 lesson: declaring min-waves 3 caps the allocator at ~84 VGPRs and
// force-spills the whole array to scratch (59 GB of HBM traffic, 8x slower).
template<int OFF, int NF4>
__device__ __forceinline__ float dot4(const unsigned (&w)[NWREG], const float4* in, float acc) {
    float a0 = acc, a1 = 0.f, a2 = 0.f, a3 = 0.f;
    #pragma unroll
    for (int i = 0; i < NF4; ++i) {
        float4 d = in[i];
        unsigned u0 = w[OFF + 2 * i], u1 = w[OFF + 2 * i + 1];
        a0 = fmaf(unpk_lo(u0), d.x, a0);
        a1 = fmaf(unpk_hi(u0), d.y, a1);
        a2 = fmaf(unpk_lo(u1), d.z, a2);
        a3 = fmaf(unpk_hi(u1), d.w, a3);
    }
    return (a0 + a1) + (a2 + a3);
}

__global__ __launch_bounds__(NTHREADS, 1)
void rnn_fused(const void* __restrict__ x,
               const void* __restrict__ dense_w, const void* __restrict__ dense_b,
               const void* __restrict__ vad_w_ih, const void* __restrict__ vad_w_hh,
               const void* __restrict__ vad_b_ih, const void* __restrict__ vad_b_hh,
               const void* __restrict__ vad_out_w, const void* __restrict__ vad_out_b,
               const void* __restrict__ noise_w_ih, const void* __restrict__ noise_w_hh,
               const void* __restrict__ noise_b_ih, const void* __restrict__ noise_b_hh,
               const void* __restrict__ den_w_ih, const void* __restrict__ den_w_hh,
               const void* __restrict__ den_b_ih, const void* __restrict__ den_b_hh,
               const void* __restrict__ out_w, const void* __restrict__ out_b,
               void* __restrict__ d_out) {
    // ---- LDS (~6 KiB): only activations/state/partials; weights live in VGPRs ----
    __shared__ __align__(16) float sXT[44];    // x(t) fp32 (+pad zeros)
    __shared__ __align__(16) float sTMP[24];   // dense out
    __shared__ __align__(16) float sHV[24];    // h_vad
    __shared__ __align__(16) float sHN[48];    // h_noise
    __shared__ __align__(16) float sHD[96];    // h_den
    __shared__ __align__(16) float sHR[96];    // relu(h_den)
    __shared__ __align__(16) float sNIN[92];   // [tmp | vad | x] (+pad)
    __shared__ __align__(16) float sDIN[116];  // [vad | relu(noise) | x] (+pad)
    __shared__ float sNPI[144], sNPH[144];     // noise partials
    __shared__ float sGI[288], sGH[288];       // den partials
    __shared__ int sBad;

    const int tid = threadIdx.x;
    const int b = blockIdx.x;
    const int nt = NTHREADS;

    // ---- dtype detection (validated in earlier rounds) ----
    if (tid == 0) sBad = 0;
    __syncthreads();
    {
        const unsigned* w = (const unsigned*)dense_w;
        for (int i = tid; i < 500; i += nt) {
            float av = fabsf(unpk_lo(w[i]));
            if (!(av <= 1e3f)) { atomicAdd(&sBad, 1); break; }
        }
    }
    __syncthreads();
    const bool F32 = (sBad > 0);

    const float* xbf = (const float*)x + (size_t)b * TT * FF;
    const __hip_bfloat16* xbh = (const __hip_bfloat16*)x + (size_t)b * TT * FF;
    float* odf = (float*)d_out;
    __hip_bfloat16* odh = (__hip_bfloat16*)d_out;
    float* ovf = odf + (size_t)BB * TT * 22;
    __hip_bfloat16* ovh = odh + (size_t)BB * TT * 22;

    // ---- role-partitioned weight registers ----
    // tid   0-287: wreg[0..57]  = den_w_ih row tid (57w + zero pad)
    // tid  96-119:   + wreg[58..79] = dense row (tid-96) (21w + pad)
    // tid 288-311: wreg[0..71]  = vad fused: 3 ih rows, 3 hh rows (12w each)
    // tid     312: wreg[0..11]  = vad_out row
    // tid 320-607: wreg[0..47]  = den_w_hh row (tid-320)
    // tid 320-463:   + wreg[48..93] = noise_w_ih row (tid-320) (45w + pad)
    // tid 464-607:   + wreg[48..71] = noise_w_hh row (tid-464)
    // tid 608-629: wreg[0..47]  = out_w row (tid-608)
    unsigned wreg[NWREG];
    #pragma unroll
    for (int i = 0; i < NWREG; ++i) wreg[i] = 0u;
    float b_main = 0.f, b_aux = 0.f;
    float bv0 = 0.f, bv1 = 0.f, bv2 = 0.f, bv3 = 0.f, bv4 = 0.f, bv5 = 0.f;
    float hvreg = 0.f;

    if (tid < 288) {
        #pragma unroll
        for (int i = 0; i < 57; ++i)
            wreg[i] = pack2(gld(den_w_ih, tid * 114 + 2 * i, F32),
                            gld(den_w_ih, tid * 114 + 2 * i + 1, F32));
        b_main = gld(den_b_ih, tid, F32);
        if (tid >= 96 && tid < 120) {
            int o = tid - 96;
            #pragma unroll
            for (int i = 0; i < 21; ++i)
                wreg[58 + i] = pack2(gld(dense_w, o * 42 + 2 * i, F32),
                                     gld(dense_w, o * 42 + 2 * i + 1, F32));
            b_aux = gld(dense_b, o, F32);
        }
    } else if (tid < 312) {
        int o = tid - 288;
        #pragma unroll
        for (int g = 0; g < 3; ++g) {
            #pragma unroll
            for (int i = 0; i < 12; ++i) {
                wreg[g * 12 + i]      = pack2(gld(vad_w_ih, (g * 24 + o) * 24 + 2 * i, F32),
                                              gld(vad_w_ih, (g * 24 + o) * 24 + 2 * i + 1, F32));
                wreg[36 + g * 12 + i] = pack2(gld(vad_w_hh, (g * 24 + o) * 24 + 2 * i, F32),
                                              gld(vad_w_hh, (g * 24 + o) * 24 + 2 * i + 1, F32));
            }
        }
        bv0 = gld(vad_b_ih, o, F32);      bv1 = gld(vad_b_ih, 24 + o, F32);
        bv2 = gld(vad_b_ih, 48 + o, F32); bv3 = gld(vad_b_hh, o, F32);
        bv4 = gld(vad_b_hh, 24 + o, F32); bv5 = gld(vad_b_hh, 48 + o, F32);
    } else if (tid == 312) {
        #pragma unroll
        for (int i = 0; i < 12; ++i)
            wreg[i] = pack2(gld(vad_out_w, 2 * i, F32), gld(vad_out_w, 2 * i + 1, F32));
        b_main = gld(vad_out_b, 0, F32);
    } else if (tid >= 320 && tid < 608) {
        int o = tid - 320;
        #pragma unroll
        for (int i = 0; i < 48; ++i)
            wreg[i] = pack2(gld(den_w_hh, o * 96 + 2 * i, F32),
                            gld(den_w_hh, o * 96 + 2 * i + 1, F32));
        b_main = gld(den_b_hh, o, F32);
        if (o < 144) {
            #pragma unroll
            for (int i = 0; i < 45; ++i)
                wreg[48 + i] = pack2(gld(noise_w_ih, o * 90 + 2 * i, F32),
                                     gld(noise_w_ih, o * 90 + 2 * i + 1, F32));
            b_aux = gld(noise_b_ih, o, F32);
        } else {
            int o2 = o - 144;
            #pragma unroll
            for (int i = 0; i < 24; ++i)
                wreg[48 + i] = pack2(gld(noise_w_hh, o2 * 48 + 2 * i, F32),
                                     gld(noise_w_hh, o2 * 48 + 2 * i + 1, F32));
            b_aux = gld(noise_b_hh, o2, F32);
        }
    } else if (tid >= 608 && tid < 630) {
        int o = tid - 608;
        #pragma unroll
        for (int i = 0; i < 48; ++i)
            wreg[i] = pack2(gld(out_w, o * 96 + 2 * i, F32),
                            gld(out_w, o * 96 + 2 * i + 1, F32));
        b_main = gld(out_b, o, F32);
    }

    // ---- prologue: zero state, stage x(0), prefetch x(1) ----
    for (int i = tid; i < 24; i += nt) { sHV[i] = 0.f; sTMP[i] = 0.f; }
    for (int i = tid; i < 48; i += nt) sHN[i] = 0.f;
    for (int i = tid; i < 96; i += nt) { sHD[i] = 0.f; sHR[i] = 0.f; }
    if (tid < 2) { sXT[42 + tid] = 0.f; sNIN[90 + tid] = 0.f; sDIN[114 + tid] = 0.f; }
    if (tid < FF) {
        float v = F32 ? xbf[tid] : bf2f(xbh[tid]);
        sXT[tid] = v; sNIN[48 + tid] = v; sDIN[72 + tid] = v;
    }
    float xreg = 0.f;
    if (tid >= 464 && tid < 464 + FF) {
        int j = tid - 464;
        xreg = F32 ? xbf[FF + j] : bf2f(xbh[FF + j]);
    }
    __syncthreads();
    // dense(0)
    if (tid >= 96 && tid < 120) {
        int o = tid - 96;
        float v = tanh_fast(dot4<58, 11>(wreg, (const float4*)sXT, b_aux));
        sTMP[o] = v; sNIN[o] = v;
    }
    __syncthreads();

    for (int t = 0; t < TT; ++t) {
        // ---- S2: den hh [waves 5-9] || vad fused GRU [wave 4] || out head(t-1) [wave 9 hi] ----
        if (tid >= 320 && tid < 608) {
            sGH[tid - 320] = dot4<0, 24>(wreg, (const float4*)sHD, b_main);
        } else if (tid >= 288 && tid < 312) {
            // all 24 vad threads are in wave 4: lockstep read-then-write of sHV is safe
            int o = tid - 288;
            const float4* tmp4 = (const float4*)sTMP;
            const float4* hv4 = (const float4*)sHV;
            float xr = dot4<0,  6>(wreg, tmp4, bv0);
            float xz = dot4<12, 6>(wreg, tmp4, bv1);
            float xn = dot4<24, 6>(wreg, tmp4, bv2);
            float hr = dot4<36, 6>(wreg, hv4, bv3);
            float hz = dot4<48, 6>(wreg, hv4, bv4);
            float hn = dot4<60, 6>(wreg, hv4, bv5);
            float r = sig(xr + hr);
            float z = sig(xz + hz);
            float n = tanh_fast(xn + r * hn);
            float h = (1.f - z) * n + z * hvreg;
            hvreg = h;
            sHV[o] = h; sNIN[24 + o] = h; sDIN[o] = h;
        } else if (tid >= 608 && tid < 630) {
            if (t > 0) {
                int o = tid - 608;
                float v = sig(dot4<0, 24>(wreg, (const float4*)sHR, b_main));
                size_t oi = ((size_t)b * TT + (t - 1)) * 22 + o;
                if (F32) odf[oi] = v; else odh[oi] = __float2bfloat16(v);
            }
        }
        __syncthreads();

        // ---- S3: noise ih [waves 5-7] || noise hh [waves 7-9] || vad_out(t) ----
        if (tid >= 320 && tid < 464) {
            sNPI[tid - 320] = dot4<48, 23>(wreg, (const float4*)sNIN, b_aux);
        } else if (tid >= 464 && tid < 608) {
            sNPH[tid - 464] = dot4<48, 12>(wreg, (const float4*)sHN, b_aux);
        } else if (tid == 312) {
            float v = sig(dot4<0, 6>(wreg, (const float4*)sHV, b_main));
            size_t oi = (size_t)b * TT + t;
            if (F32) ovf[oi] = v; else ovh[oi] = __float2bfloat16(v);
        }
        __syncthreads();

        // ---- S4: noise update [wave 0] ----
        if (tid < 48) {
            float r = sig(sNPI[tid] + sNPH[tid]);
            float z = sig(sNPI[48 + tid] + sNPH[48 + tid]);
            float n = tanh_fast(sNPI[96 + tid] + r * sNPH[96 + tid]);
            float h = (1.f - z) * n + z * sHN[tid];
            sHN[tid] = h;
            sDIN[24 + tid] = fmaxf(h, 0.f);
        }
        __syncthreads();

        // ---- S5: den ih [waves 0-4] || x(t+1) -> sXT,sNIN [wave 7] ----
        if (tid < 288) {
            sGI[tid] = dot4<0, 29>(wreg, (const float4*)sDIN, b_main);
        } else if (tid >= 464 && tid < 464 + FF) {
            int j = tid - 464;
            sXT[j] = xreg; sNIN[48 + j] = xreg;
            int t2 = (t + 2 < TT) ? (t + 2) : (TT - 1);
            xreg = F32 ? xbf[t2 * FF + j] : bf2f(xbh[t2 * FF + j]);
        }
        __syncthreads();

        // ---- S6: den update [waves 0-1] || dense(t+1) [w1/w2] || x->sDIN [wave 2] ----
        if (tid < 96) {
            float r = sig(sGI[tid] + sGH[tid]);
            float z = sig(sGI[96 + tid] + sGH[96 + tid]);
            float n = tanh_fast(sGI[192 + tid] + r * sGH[192 + tid]);
            float h = (1.f - z) * n + z * sHD[tid];
            sHD[tid] = h;
            sHR[tid] = fmaxf(h, 0.f);
        } else if (tid < 120) {
            int o = tid - 96;
            float v = tanh_fast(dot4<58, 11>(wreg, (const float4*)sXT, b_aux));
            sTMP[o] = v; sNIN[o] = v;
        } else if (tid >= 128 && tid < 128 + FF) {
            int j = tid - 128;
            sDIN[72 + j] = sXT[j];
        }
        __syncthreads();
    }

    // ---- epilogue: out head for t = TT-1 ----
    if (tid >= 608 && tid < 630) {
        int o = tid - 608;
        float v = sig(dot4<0, 24>(wreg, (const float4*)sHR, b_main));
        size_t oi = ((size_t)b * TT + (TT - 1)) * 22 + o;
        if (F32) odf[oi] = v; else odh[oi] = __float2bfloat16(v);
    }
}

extern "C" void kernel_launch(void* const* d_in, const int* in_sizes, int n_in,
                              void* d_out, int out_size, void* d_ws, size_t ws_size,
                              hipStream_t stream) {
    hipLaunchKernelGGL(rnn_fused, dim3(BB), dim3(NTHREADS), 0, stream,
                       d_in[0], d_in[1], d_in[2],
                       d_in[3], d_in[4], d_in[5], d_in[6],
                       d_in[7], d_in[8],
                       d_in[9], d_in[10], d_in[11], d_in[12],
                       d_in[13], d_in[14], d_in[15], d_in[16],
                       d_in[17], d_in[18], d_out);
}